// Round 5
// baseline (29.046 us; speedup 1.0000x reference)
//
#include <hip/hip_runtime.h>

#define SCALE 0.0625f

constexpr int HF = 64, WF = 64, CF = 256, BF = 8;
constexpr int P = 7, S = 4;
constexpr int BINS = P * P;                 // 49
constexpr int NROI = 256;
constexpr int SROW = 257;                   // LDS row pad: odd -> bank step 1 on read

// ---------------------------------------------------------------------------
// Kernel 1: transpose (B, C, H*W) -> (B, H*W, C) so channel gathers coalesce.
// ---------------------------------------------------------------------------
__global__ __launch_bounds__(256) void transpose_kernel(const float* __restrict__ in,
                                                        float* __restrict__ out) {
    __shared__ float tile[32][33];
    const int b   = blockIdx.z;
    const int c0  = blockIdx.y * 32;
    const int hw0 = blockIdx.x * 32;
    const int tx  = threadIdx.x & 31;
    const int ty  = threadIdx.x >> 5;

    const float* src = in + ((size_t)b * CF + c0) * (HF * WF) + hw0;
    #pragma unroll
    for (int i = 0; i < 32; i += 8)
        tile[ty + i][tx] = src[(size_t)(ty + i) * (HF * WF) + tx];
    __syncthreads();

    float* dst = out + ((size_t)b * (HF * WF) + hw0) * CF + c0;
    #pragma unroll
    for (int i = 0; i < 32; i += 8)
        dst[(size_t)(ty + i) * CF + tx] = tile[tx][ty + i];
}

// ---------------------------------------------------------------------------
// Kernel 2: block-per-roi separable deformable PS-RoI pooling.
// 1024 threads = 16 waves; wave w does bins w, w+16, ... (R3's proven math).
// All 49 bins staged in LDS, then the roi's whole 49KB output slice is
// written contiguously (full lines, nontemporal). L1 gets the ~3.5x
// cell-overlap reuse across the roi's bins (one CU owns the whole roi).
// ---------------------------------------------------------------------------
__global__ __launch_bounds__(1024) void dcn_pool_roi(const float* __restrict__ xt,
                                                     const float* __restrict__ rois,
                                                     const float* __restrict__ offset,
                                                     float* __restrict__ out) {
    __shared__ float stage[BINS * SROW];       // 49*257*4 = 50372 B
    const int n    = blockIdx.x;
    const int lane = threadIdx.x & 63;
    const int wv   = threadIdx.x >> 6;         // 0..15

    // ---- roi-uniform math ----
    const float* r = rois + n * 5;
    const int   batch  = (int)r[0];
    const float roi_sw = rintf(r[1]) * SCALE - 0.5f;   // rintf == jnp.round (half-even)
    const float roi_sh = rintf(r[2]) * SCALE - 0.5f;
    const float roi_w  = fmaxf((rintf(r[3]) + 1.0f) * SCALE - 0.5f - roi_sw, 0.1f);
    const float roi_h  = fmaxf((rintf(r[4]) + 1.0f) * SCALE - 0.5f - roi_sh, 0.1f);
    const float bin_w  = roi_w / 7.0f;
    const float bin_h  = roi_h / 7.0f;
    const float sub_w  = bin_w * 0.25f;
    const float sub_h  = bin_h * 0.25f;

    // batch stride = HF*WF*CF = 2^20 floats
    const float* bp = xt + ((size_t)batch << 20) + (lane << 2);

    for (int bin = wv; bin < BINS; bin += 16) {
        const int ph = bin / 7;
        const int pw = bin - ph * 7;

        const float tx = offset[n * 98 + bin] * 0.1f;
        const float ty = offset[n * 98 + 49 + bin] * 0.1f;
        const float wstart = (float)pw * bin_w + roi_sw + tx * roi_w;
        const float hstart = (float)ph * bin_h + roi_sh + ty * roi_h;

        // ---- separable axis weights (sample spread 3*sub_w <= ~1.5 px
        //      -> floor span <= 2 -> 4 cells per axis suffice) ----
        float WX0 = 0.f, WX1 = 0.f, WX2 = 0.f, WX3 = 0.f, cw = 0.f;
        const int xbase = (int)fminf(fmaxf(wstart, 0.f), 63.f);
        #pragma unroll
        for (int i = 0; i < 4; ++i) {
            const float p  = wstart + (float)i * sub_w;
            const float vf = (p >= -0.5f && p <= 63.5f) ? 1.f : 0.f;
            cw += vf;
            const float pc = fminf(fmaxf(p, 0.f), 63.f);
            const float fx = floorf(pc);
            const float dx = pc - fx;
            const int   j  = (int)fx - xbase;
            const float lo = vf * (1.f - dx);
            const float hi = vf * dx;
            if (j == 0)      { WX0 += lo; WX1 += hi; }
            else if (j == 1) { WX1 += lo; WX2 += hi; }
            else if (j == 2) { WX2 += lo; WX3 += hi; }
            else             { WX3 += lo; }
        }

        float WY0 = 0.f, WY1 = 0.f, WY2 = 0.f, WY3 = 0.f, chh = 0.f;
        const int ybase = (int)fminf(fmaxf(hstart, 0.f), 63.f);
        #pragma unroll
        for (int i = 0; i < 4; ++i) {
            const float p  = hstart + (float)i * sub_h;
            const float vf = (p >= -0.5f && p <= 63.5f) ? 1.f : 0.f;
            chh += vf;
            const float pc = fminf(fmaxf(p, 0.f), 63.f);
            const float fy = floorf(pc);
            const float dy = pc - fy;
            const int   j  = (int)fy - ybase;
            const float lo = vf * (1.f - dy);
            const float hi = vf * dy;
            if (j == 0)      { WY0 += lo; WY1 += hi; }
            else if (j == 1) { WY1 += lo; WY2 += hi; }
            else if (j == 2) { WY2 += lo; WY3 += hi; }
            else             { WY3 += lo; }
        }

        const int xi0 = xbase << 8;
        const int xi1 = min(xbase + 1, 63) << 8;
        const int xi2 = min(xbase + 2, 63) << 8;
        const int xi3 = min(xbase + 3, 63) << 8;

        float a0 = 0.f, a1 = 0.f, a2 = 0.f, a3 = 0.f;

#define DCN_ROW(WYv, cy)                                                             \
    if (WYv != 0.f) {                                                                \
        const float* rp = bp + ((size_t)min(ybase + cy, 63) << 14);                  \
        const float4 v0 = *(const float4*)(rp + xi0);                                \
        const float4 v1 = *(const float4*)(rp + xi1);                                \
        const float4 v2 = *(const float4*)(rp + xi2);                                \
        const float4 v3 = *(const float4*)(rp + xi3);                                \
        const float w0 = WYv * WX0, w1 = WYv * WX1, w2 = WYv * WX2, w3 = WYv * WX3;  \
        a0 = fmaf(w0, v0.x, a0); a1 = fmaf(w0, v0.y, a1);                            \
        a2 = fmaf(w0, v0.z, a2); a3 = fmaf(w0, v0.w, a3);                            \
        a0 = fmaf(w1, v1.x, a0); a1 = fmaf(w1, v1.y, a1);                            \
        a2 = fmaf(w1, v1.z, a2); a3 = fmaf(w1, v1.w, a3);                            \
        a0 = fmaf(w2, v2.x, a0); a1 = fmaf(w2, v2.y, a1);                            \
        a2 = fmaf(w2, v2.z, a2); a3 = fmaf(w2, v2.w, a3);                            \
        a0 = fmaf(w3, v3.x, a0); a1 = fmaf(w3, v3.y, a1);                            \
        a2 = fmaf(w3, v3.z, a2); a3 = fmaf(w3, v3.w, a3);                            \
    }

        DCN_ROW(WY0, 0)
        DCN_ROW(WY1, 1)
        DCN_ROW(WY2, 2)
        DCN_ROW(WY3, 3)
#undef DCN_ROW

        const float cf  = cw * chh;                 // == reference cnt (separable validity)
        const float inv = (cf > 0.f) ? (1.0f / cf) : 0.0f;

        float* sp = stage + bin * SROW + (lane << 2);
        sp[0] = a0 * inv;
        sp[1] = a1 * inv;
        sp[2] = a2 * inv;
        sp[3] = a3 * inv;
    }

    __syncthreads();

    // ---- contiguous write of this roi's (C,P,P) slice: 12544 floats ----
    const size_t ob = (size_t)n * (CF * BINS);
    for (int idx = threadIdx.x; idx < CF * BINS; idx += 1024) {
        const int c   = idx / BINS;                 // magic-mul
        const int bin = idx - c * BINS;
        __builtin_nontemporal_store(stage[bin * SROW + c], &out[ob + idx]);
    }
}

// ---------------------------------------------------------------------------
// Fallback: direct (B,C,H,W) gather, used only if workspace too small or
// unexpected shapes. Correct but slow.
// ---------------------------------------------------------------------------
__global__ __launch_bounds__(256) void dcn_pool_fallback(const float* __restrict__ x,
                                                         const float* __restrict__ rois,
                                                         const float* __restrict__ offset,
                                                         float* __restrict__ out) {
    const int n   = blockIdx.x / BINS;
    const int bin = blockIdx.x % BINS;
    const int ph  = bin / P;
    const int pw  = bin % P;
    const int c   = threadIdx.x;

    const float* r = rois + n * 5;
    const int   batch  = (int)r[0];
    const float roi_sw = rintf(r[1]) * SCALE - 0.5f;
    const float roi_sh = rintf(r[2]) * SCALE - 0.5f;
    const float roi_w  = fmaxf((rintf(r[3]) + 1.0f) * SCALE - 0.5f - roi_sw, 0.1f);
    const float roi_h  = fmaxf((rintf(r[4]) + 1.0f) * SCALE - 0.5f - roi_sh, 0.1f);
    const float bin_w  = roi_w / 7.0f;
    const float bin_h  = roi_h / 7.0f;
    const float sub_w  = bin_w * 0.25f;
    const float sub_h  = bin_h * 0.25f;

    const float tx = offset[n * 98 + ph * 7 + pw] * 0.1f;
    const float ty = offset[n * 98 + 49 + ph * 7 + pw] * 0.1f;

    const float wstart = (float)pw * bin_w + roi_sw + tx * roi_w;
    const float hstart = (float)ph * bin_h + roi_sh + ty * roi_h;

    float sum = 0.0f;
    int   cnt = 0;
    for (int ih = 0; ih < S; ++ih) {
        for (int iw = 0; iw < S; ++iw) {
            const float wpos = wstart + (float)iw * sub_w;
            const float hpos = hstart + (float)ih * sub_h;
            if (wpos >= -0.5f && wpos <= (float)WF - 0.5f &&
                hpos >= -0.5f && hpos <= (float)HF - 0.5f) {
                const float wc_ = fminf(fmaxf(wpos, 0.0f), (float)(WF - 1));
                const float hc_ = fminf(fmaxf(hpos, 0.0f), (float)(HF - 1));
                const float fx = floorf(wc_);
                const float fy = floorf(hc_);
                const int x0 = (int)fx, x1i = (int)ceilf(wc_);
                const int y0 = (int)fy, y1i = (int)ceilf(hc_);
                const float dx = wc_ - fx, dy = hc_ - fy;
                const float* bbp = x + ((size_t)batch * CF + c) * (HF * WF);
                const float v00 = bbp[y0 * WF + x0];
                const float v01 = bbp[y0 * WF + x1i];
                const float v10 = bbp[y1i * WF + x0];
                const float v11 = bbp[y1i * WF + x1i];
                sum += (1.0f - dx) * (1.0f - dy) * v00 + dx * (1.0f - dy) * v01
                     + (1.0f - dx) * dy * v10 + dx * dy * v11;
                ++cnt;
            }
        }
    }
    out[((size_t)n * CF + c) * BINS + bin] = (cnt > 0) ? (sum / (float)cnt) : 0.0f;
}

extern "C" void kernel_launch(void* const* d_in, const int* in_sizes, int n_in,
                              void* d_out, int out_size, void* d_ws, size_t ws_size,
                              hipStream_t stream) {
    const float* x      = (const float*)d_in[0];
    const float* rois   = (const float*)d_in[1];
    const float* offset = (const float*)d_in[2];
    float*       out    = (float*)d_out;

    const int N = in_sizes[1] / 5;
    const size_t need = (size_t)BF * CF * HF * WF * sizeof(float);

    if (ws_size >= need && N == NROI) {
        float* xt = (float*)d_ws;
        dim3 tgrid(HF * WF / 32, CF / 32, BF);
        transpose_kernel<<<tgrid, 256, 0, stream>>>(x, xt);
        dcn_pool_roi<<<NROI, 1024, 0, stream>>>(xt, rois, offset, out);
    } else {
        dcn_pool_fallback<<<N * BINS, 256, 0, stream>>>(x, rois, offset, out);
    }
}